// Round 10
// baseline (208.299 us; speedup 1.0000x reference)
//
#include <hip/hip_runtime.h>

// ---------------------------------------------------------------------------
// MultiHeadAttention forward, MI355X (gfx950), bf16 MFMA pipeline. Round 9:
//  - GEMMs: BM=128 BN=128 BK=64 (2x MFMA per staged byte vs BN=64), dbuf.
//  - attn: KBLK=128 staged per tile (2x64-k compute halves, Ps reused),
//    16 barriers total, XCD-swizzled grid (16 qtiles of a bh -> same XCD).
//  - exp2-direct softmax (Wq pre-scaled by log2e), s_setprio on MFMA.
// ---------------------------------------------------------------------------

typedef __attribute__((ext_vector_type(4))) float  f32x4;
typedef __attribute__((ext_vector_type(8))) __bf16 bf16x8;
typedef __attribute__((ext_vector_type(4))) __bf16 bf16x4;

#define SLEN 2048
#define BSZ  2
#define DMODEL 1024
#define NHEAD 16
#define DHEAD 64
#define D3 (3 * DMODEL)   // 3072

__device__ __forceinline__ void async16(void* lds, const void* g) {
    __builtin_amdgcn_global_load_lds(
        (const __attribute__((address_space(1))) unsigned int*)g,
        (__attribute__((address_space(3))) unsigned int*)lds, 16, 0, 0);
}

__device__ __forceinline__ f32x4 mfma16(bf16x8 a, bf16x8 b, f32x4 c) {
    return __builtin_amdgcn_mfma_f32_16x16x32_bf16(a, b, c, 0, 0, 0);
}

// ---------------------------- fused convert fp32 -> bf16 (w/ scale) --------
struct CvtArgs {
    const float* src[7];
    __bf16* dst[7];
    int n4[7];
    float scale[7];
};
__global__ void cvt_all(CvtArgs a) {
    const int t = blockIdx.y;
    const float* __restrict__ src = a.src[t];
    __bf16* __restrict__ dst = a.dst[t];
    const int n4 = a.n4[t];
    const float sc = a.scale[t];
    const int stride = gridDim.x * blockDim.x;
    for (int i = blockIdx.x * blockDim.x + threadIdx.x; i < n4; i += stride) {
        float4 v = ((const float4*)src)[i];
        bf16x4 o;
        o[0] = (__bf16)(v.x * sc); o[1] = (__bf16)(v.y * sc);
        o[2] = (__bf16)(v.z * sc); o[3] = (__bf16)(v.w * sc);
        ((bf16x4*)dst)[i] = o;
    }
}

// ---------------------------- mask all-nonzero flag ------------------------
__global__ void mask_allones(const int* __restrict__ mask, int n4, unsigned int* __restrict__ flag) {
    int stride = gridDim.x * blockDim.x;
    bool ok = true;
    for (int i = blockIdx.x * blockDim.x + threadIdx.x; i < n4; i += stride) {
        int4 v = ((const int4*)mask)[i];
        ok = ok && v.x && v.y && v.z && v.w;
    }
    if (!ok) atomicAnd(flag, 0u);
}

// ---------------------------- GEMM core: 128x128x64 dbuf -------------------
// 256 threads (4 waves 2x2), per-wave 64x64 output. A[M][K], B[N][K] row-major.
template <typename CT>
__device__ __forceinline__ void gemm_core(const char* Ab, const char* Bb, int K,
                                          CT* Cv, size_t crow0, size_t ccol0,
                                          size_t ldc, __bf16* At0, __bf16* At1,
                                          __bf16* Bt0, __bf16* Bt1) {
    const int tid = threadIdx.x;
    const int lane = tid & 63, wv = tid >> 6;
    const int l15 = lane & 15, l4 = lane >> 4;
    const int wr = wv >> 1, wc = wv & 1;
    const int srow = lane >> 3;
    const int sbyte = (((lane & 7) ^ srow) << 4);
    __bf16* At[2] = {At0, At1};
    __bf16* Bt[2] = {Bt0, Bt1};

    f32x4 acc[4][4];
#pragma unroll
    for (int m = 0; m < 4; m++)
#pragma unroll
        for (int n = 0; n < 4; n++)
#pragma unroll
            for (int r = 0; r < 4; r++) acc[m][n][r] = 0.0f;

    auto stage = [&](int buf, int k0) {
#pragma unroll
        for (int i = 0; i < 8; i++) {
            int c = wv * 8 + i;
            if (c < 16) {
                int row = c * 8 + srow;
                async16(&At[buf][c * 512], Ab + ((size_t)row * K + k0) * 2 + sbyte);
            } else {
                int row = (c - 16) * 8 + srow;
                async16(&Bt[buf][(c - 16) * 512], Bb + ((size_t)row * K + k0) * 2 + sbyte);
            }
        }
    };

    stage(0, 0);
    __syncthreads();
    int cur = 0;
    for (int k0 = 0; k0 < K; k0 += 64) {
        if (k0 + 64 < K) stage(cur ^ 1, k0 + 64);
#pragma unroll
        for (int kk = 0; kk < 2; kk++) {
            bf16x8 af[4], bfr[4];
#pragma unroll
            for (int m = 0; m < 4; m++) {
                int row = wr * 64 + m * 16 + l15;
                int col = (kk * 32 + l4 * 8) ^ ((row & 7) << 3);
                af[m] = *(const bf16x8*)&At[cur][row * 64 + col];
            }
#pragma unroll
            for (int n = 0; n < 4; n++) {
                int row = wc * 64 + n * 16 + l15;
                int col = (kk * 32 + l4 * 8) ^ ((row & 7) << 3);
                bfr[n] = *(const bf16x8*)&Bt[cur][row * 64 + col];
            }
#pragma unroll
            for (int m = 0; m < 4; m++)
#pragma unroll
                for (int n = 0; n < 4; n++)
                    acc[m][n] = mfma16(af[m], bfr[n], acc[m][n]);
        }
        __syncthreads();
        cur ^= 1;
    }

    const int lane2 = threadIdx.x & 63;
    const int L15 = lane2 & 15, L4 = lane2 >> 4;
#pragma unroll
    for (int m = 0; m < 4; m++)
#pragma unroll
        for (int n = 0; n < 4; n++)
#pragma unroll
            for (int r = 0; r < 4; r++) {
                size_t row = crow0 + wr * 64 + m * 16 + L4 * 4 + r;
                size_t col = ccol0 + wc * 64 + n * 16 + L15;
                Cv[row * ldc + col] = (CT)acc[m][n][r];
            }
}

// fused QKV projection: C[4096][3072] = A_sel @ W[3072][1024]^T
__global__ __launch_bounds__(256, 2) void gemm_qkv(const __bf16* __restrict__ Xq,
                                                   const __bf16* __restrict__ Xk,
                                                   const __bf16* __restrict__ Xv,
                                                   const __bf16* __restrict__ W,
                                                   __bf16* __restrict__ C) {
    __shared__ __bf16 At[2][128 * 64];
    __shared__ __bf16 Bt[2][128 * 64];
    const int bm = blockIdx.x, bn = blockIdx.y;  // bn 0..23
    const __bf16* A = (bn < 8) ? Xq : (bn < 16) ? Xk : Xv;
    gemm_core<__bf16>((const char*)(A + (size_t)bm * 128 * DMODEL),
                      (const char*)(W + (size_t)bn * 128 * DMODEL), DMODEL,
                      C, (size_t)bm * 128, (size_t)bn * 128, D3,
                      At[0], At[1], Bt[0], Bt[1]);
}

// out GEMM: out[4096][1024] = ATT @ Wo^T, fp32 out
__global__ __launch_bounds__(256, 2) void gemm_out(const __bf16* __restrict__ A,
                                                   const __bf16* __restrict__ B,
                                                   float* __restrict__ Cv) {
    __shared__ __bf16 At[2][128 * 64];
    __shared__ __bf16 Bt[2][128 * 64];
    const int bm = blockIdx.x, bn = blockIdx.y;
    gemm_core<float>((const char*)(A + (size_t)bm * 128 * DMODEL),
                     (const char*)(B + (size_t)bn * 128 * DMODEL), DMODEL,
                     Cv, (size_t)bm * 128, (size_t)bn * 128, DMODEL,
                     At[0], At[1], Bt[0], Bt[1]);
}

// ---------------------------- V transpose ----------------------------------
// QKV[(s*BS+b)*3072 + 2048 + h*64 + d]  ->  Vt[((b*16+h)*64 + d)*2048 + s]
__global__ __launch_bounds__(256) void transpose_v(const __bf16* __restrict__ QKV,
                                                   __bf16* __restrict__ Vt) {
    __shared__ __bf16 t[64][72];
    const int stile = blockIdx.x;
    const int bh = blockIdx.y;
    const int b = bh >> 4, h = bh & 15;
    const int tid = threadIdx.x;
    {
        int sr = tid >> 2, d0 = (tid & 3) * 16;
        const __bf16* src = QKV + ((size_t)((stile * 64 + sr) * BSZ + b) * D3 + 2 * DMODEL + h * 64 + d0);
        *(bf16x8*)&t[sr][d0]     = *(const bf16x8*)src;
        *(bf16x8*)&t[sr][d0 + 8] = *(const bf16x8*)(src + 8);
    }
    __syncthreads();
    {
        int d = tid >> 2, s0 = (tid & 3) * 16;
        bf16x8 o1, o2;
#pragma unroll
        for (int j = 0; j < 8; j++) { o1[j] = t[s0 + j][d]; o2[j] = t[s0 + 8 + j][d]; }
        __bf16* dst = Vt + ((size_t)(bh * 64 + d) * SLEN + stile * 64 + s0);
        *(bf16x8*)dst = o1;
        *(bf16x8*)(dst + 8) = o2;
    }
}

// ---------------------------- attention ------------------------------------
// grid 512; XCD swizzle: blk&7 -> xcd, all 16 qtiles of a bh on one XCD.
// QBLK=128 (4 waves x 32 q), KBLK=128 staged (2x64-k halves), dbuf, 16 barriers.
__global__ __launch_bounds__(256, 2) void attn_fwd(const __bf16* __restrict__ QKV,
                                                   const __bf16* __restrict__ Vt,
                                                   const int* __restrict__ mask,
                                                   const unsigned int* __restrict__ flag,
                                                   __bf16* __restrict__ Attn) {
    __shared__ __bf16 Kt[2][2][64 * 64];   // [buf][kh][k][d]
    __shared__ __bf16 Vs[2][2][64 * 64];   // [buf][kh][d][k]
    __shared__ __bf16 Ps[128 * 64];        // [q][k64] (wave-private rows)
    const int tid = threadIdx.x;
    const int lane = tid & 63, wv = tid >> 6;
    const int l15 = lane & 15, l4 = lane >> 4;
    // XCD swizzle: 512 blocks, 8 XCDs, 64 blocks/XCD = 4 bh x 16 qt
    const int blk = blockIdx.x;
    const int xcd = blk & 7, idx = blk >> 3;
    const int bh = xcd + (idx >> 4) * 8;
    const int qt = idx & 15;
    const int b = bh >> 4, h = bh & 15;
    const bool allones = (*flag != 0u);
    const int srow = lane >> 3;
    const int sbyte = (((lane & 7) ^ srow) << 4);

    // Q fragments in registers (per wave: 32 rows x 64 d)
    bf16x8 aq[2][2];
#pragma unroll
    for (int m = 0; m < 2; m++)
#pragma unroll
        for (int kk = 0; kk < 2; kk++) {
            int qrow = qt * 128 + wv * 32 + m * 16 + l15;
            aq[m][kk] = *(const bf16x8*)(QKV + ((size_t)(qrow * BSZ + b) * D3 + h * 64 + kk * 32 + l4 * 8));
        }

    f32x4 o[2][4], lr[2];
#pragma unroll
    for (int m = 0; m < 2; m++) {
#pragma unroll
        for (int nd = 0; nd < 4; nd++)
#pragma unroll
            for (int r = 0; r < 4; r++) o[m][nd][r] = 0.0f;
#pragma unroll
        for (int r = 0; r < 4; r++) lr[m][r] = 0.0f;
    }

    const char* Kb = (const char*)QKV + ((size_t)b * D3 + DMODEL + h * 64) * 2;
    const char* Vb = (const char*)Vt + ((size_t)bh * 64) * SLEN * 2;

    // stage one 128-k tile: 16 K chunks + 16 V chunks over 4 waves
    auto stage = [&](int buf, int kt) {
#pragma unroll
        for (int i = 0; i < 8; i++) {
            int c = wv * 8 + i;  // 0..31
            if (c < 16) {
                int kh = c >> 3, ck = c & 7;
                int krow = kt * 128 + kh * 64 + ck * 8 + srow;
                async16(&Kt[buf][kh][ck * 512],
                        Kb + (size_t)krow * (BSZ * D3 * 2) + sbyte);
            } else {
                int c2 = c - 16;
                int kh = c2 >> 3, ck = c2 & 7;
                int drow = ck * 8 + srow;
                async16(&Vs[buf][kh][ck * 512],
                        Vb + (size_t)drow * (SLEN * 2) + kt * 256 + kh * 128 + sbyte);
            }
        }
    };

    stage(0, 0);
    __syncthreads();
    int cur = 0;

    for (int kt = 0; kt < SLEN / 128; kt++) {
        if (kt + 1 < SLEN / 128) stage(cur ^ 1, kt + 1);

#pragma unroll
        for (int kh = 0; kh < 2; kh++) {
            const __bf16* Kl = Kt[cur][kh];
            const __bf16* Vl = Vs[cur][kh];

            // S = Q K^T  (per wave: 32 q x 64 k)
            f32x4 s[2][4];
#pragma unroll
            for (int m = 0; m < 2; m++)
#pragma unroll
                for (int n = 0; n < 4; n++)
#pragma unroll
                    for (int r = 0; r < 4; r++) s[m][n][r] = 0.0f;
            __builtin_amdgcn_s_setprio(1);
#pragma unroll
            for (int n = 0; n < 4; n++) {
                int row = n * 16 + l15;
#pragma unroll
                for (int kk = 0; kk < 2; kk++) {
                    int col = (kk * 32 + l4 * 8) ^ ((row & 7) << 3);
                    bf16x8 bk = *(const bf16x8*)&Kl[row * 64 + col];
#pragma unroll
                    for (int m = 0; m < 2; m++)
                        s[m][n] = mfma16(aq[m][kk], bk, s[m][n]);
                }
            }
            __builtin_amdgcn_s_setprio(0);

            if (!allones) {
#pragma unroll
                for (int m = 0; m < 2; m++)
#pragma unroll
                    for (int n = 0; n < 4; n++)
#pragma unroll
                        for (int r = 0; r < 4; r++) {
                            int q = qt * 128 + wv * 32 + m * 16 + l4 * 4 + r;
                            int kg = kt * 128 + kh * 64 + n * 16 + l15;
                            if (mask[(size_t)q * SLEN + kg] == 0) s[m][n][r] = -1e20f;
                        }
            }

            // exp2-direct softmax (log2e folded into Wq)
#pragma unroll
            for (int m = 0; m < 2; m++)
#pragma unroll
                for (int n = 0; n < 4; n++)
#pragma unroll
                    for (int r = 0; r < 4; r++) {
                        float p = __builtin_amdgcn_exp2f(s[m][n][r]);
                        s[m][n][r] = p;
                        lr[m][r] += p;
                        int row = wv * 32 + m * 16 + l4 * 4 + r;
                        int col = (n * 16 + l15) ^ ((row & 7) << 3);
                        Ps[row * 64 + col] = (__bf16)p;
                    }

            // O += P V
            __builtin_amdgcn_s_setprio(1);
#pragma unroll
            for (int ks = 0; ks < 2; ks++) {
                bf16x8 ap[2];
#pragma unroll
                for (int m = 0; m < 2; m++) {
                    int prow = wv * 32 + m * 16 + l15;
                    int pcol = (ks * 32 + l4 * 8) ^ ((prow & 7) << 3);
                    ap[m] = *(const bf16x8*)&Ps[prow * 64 + pcol];
                }
#pragma unroll
                for (int nd = 0; nd < 4; nd++) {
                    int vrow = nd * 16 + l15;
                    int vcol = (ks * 32 + l4 * 8) ^ ((vrow & 7) << 3);
                    bf16x8 bv = *(const bf16x8*)&Vl[vrow * 64 + vcol];
#pragma unroll
                    for (int m = 0; m < 2; m++)
                        o[m][nd] = mfma16(ap[m], bv, o[m][nd]);
                }
            }
            __builtin_amdgcn_s_setprio(0);
        }

        __syncthreads();
        cur ^= 1;
    }

    // final row-sum reduce across the 16-lane k-slices, normalize + store
#pragma unroll
    for (int d = 1; d < 16; d <<= 1)
#pragma unroll
        for (int m = 0; m < 2; m++)
#pragma unroll
            for (int r = 0; r < 4; r++) lr[m][r] += __shfl_xor(lr[m][r], d);

#pragma unroll
    for (int m = 0; m < 2; m++) {
        f32x4 inv;
#pragma unroll
        for (int r = 0; r < 4; r++) inv[r] = 1.0f / lr[m][r];
#pragma unroll
        for (int nd = 0; nd < 4; nd++)
#pragma unroll
            for (int r = 0; r < 4; r++) {
                int qrow = qt * 128 + wv * 32 + m * 16 + l4 * 4 + r;
                Attn[((size_t)(qrow * BSZ + b)) * DMODEL + h * 64 + nd * 16 + l15] =
                    (__bf16)(o[m][nd][r] * inv[r]);
            }
    }
}

// ---------------------------- launcher -------------------------------------
extern "C" void kernel_launch(void* const* d_in, const int* in_sizes, int n_in,
                              void* d_out, int out_size, void* d_ws, size_t ws_size,
                              hipStream_t stream) {
    const float* query  = (const float*)d_in[0];
    const float* keys   = (const float*)d_in[1];
    const float* values = (const float*)d_in[2];
    const int*   mask   = (const int*)d_in[3];
    const float* Wq     = (const float*)d_in[4];
    const float* Wk     = (const float*)d_in[5];
    const float* Wv     = (const float*)d_in[6];
    const float* Wo     = (const float*)d_in[7];
    float* out = (float*)d_out;

    char* ws = (char*)d_ws;
    const size_t MB = 1024 * 1024;
    __bf16* XQ   = (__bf16*)(ws + 0);
    __bf16* XK   = (__bf16*)(ws + 8 * MB);
    __bf16* XV   = (__bf16*)(ws + 16 * MB);
    __bf16* WCAT = (__bf16*)(ws + 24 * MB);   // [3072][1024]: Wq|Wk|Wv
    __bf16* WQB  = WCAT;
    __bf16* WKB  = (__bf16*)(ws + 26 * MB);
    __bf16* WVB  = (__bf16*)(ws + 28 * MB);
    __bf16* WOB  = (__bf16*)(ws + 30 * MB);
    __bf16* QKV  = (__bf16*)(ws + 32 * MB);   // [4096][3072] = 24 MB
    __bf16* VT   = (__bf16*)(ws + 0);         // reuse XQ (free after gemm_qkv)
    __bf16* ATT  = (__bf16*)(ws + 8 * MB);    // reuse XK
    unsigned int* flag = (unsigned int*)(ws + 56 * MB);

    (void)hipMemsetAsync(flag, 0xFF, 4, stream);

    const int NTOK = SLEN * BSZ;  // 4096
    const int NBIG = NTOK * DMODEL / 4, NW = DMODEL * DMODEL / 4;
    const float LOG2E = 1.4426950408889634f;
    CvtArgs ca;
    ca.src[0] = query;  ca.dst[0] = XQ;  ca.n4[0] = NBIG; ca.scale[0] = 1.0f;
    ca.src[1] = keys;   ca.dst[1] = XK;  ca.n4[1] = NBIG; ca.scale[1] = 1.0f;
    ca.src[2] = values; ca.dst[2] = XV;  ca.n4[2] = NBIG; ca.scale[2] = 1.0f;
    ca.src[3] = Wq;     ca.dst[3] = WQB; ca.n4[3] = NW;   ca.scale[3] = LOG2E;
    ca.src[4] = Wk;     ca.dst[4] = WKB; ca.n4[4] = NW;   ca.scale[4] = 1.0f;
    ca.src[5] = Wv;     ca.dst[5] = WVB; ca.n4[5] = NW;   ca.scale[5] = 1.0f;
    ca.src[6] = Wo;     ca.dst[6] = WOB; ca.n4[6] = NW;   ca.scale[6] = 1.0f;
    cvt_all<<<dim3(256, 7), 256, 0, stream>>>(ca);

    mask_allones<<<512, 256, 0, stream>>>(mask, SLEN * SLEN / 4, flag);

    // fused QKV projection: grid (32, 24) = 768 blocks (128x128 tiles)
    gemm_qkv<<<dim3(NTOK / 128, D3 / 128), 256, 0, stream>>>(XQ, XK, XV, WCAT, QKV);

    transpose_v<<<dim3(SLEN / 64, BSZ * NHEAD), 256, 0, stream>>>(QKV, VT);

    attn_fwd<<<BSZ * NHEAD * (SLEN / 128), 256, 0, stream>>>(QKV, VT, mask, flag, ATT);

    gemm_out<<<dim3(NTOK / 128, DMODEL / 128), 256, 0, stream>>>(ATT, WOB, out);
}

// Round 11
// 135.727 us; speedup vs baseline: 1.5347x; 1.5347x over previous
//
#include <hip/hip_runtime.h>

// ---------------------------------------------------------------------------
// MultiHeadAttention forward, MI355X (gfx950), bf16 MFMA pipeline. Round 11:
//  - GEMMs: REVERT to BM=128 BN=64 BK=64 dbuf (48KB LDS, 3 blocks/CU,
//    1536/512-block grids). 128x128 regressed 2.3x (R10: latency-bound at
//    2 blocks/CU + small grid).
//  - attn: KEPT from R9 (KBLK=128 staged, 2x64 halves, XCD-swizzled grid)
//    to get its isolated measurement this round.
//  - exp2-direct softmax (Wq pre-scaled by log2e), s_setprio on MFMA.
// ---------------------------------------------------------------------------

typedef __attribute__((ext_vector_type(4))) float  f32x4;
typedef __attribute__((ext_vector_type(8))) __bf16 bf16x8;
typedef __attribute__((ext_vector_type(4))) __bf16 bf16x4;

#define SLEN 2048
#define BSZ  2
#define DMODEL 1024
#define NHEAD 16
#define DHEAD 64
#define D3 (3 * DMODEL)   // 3072

__device__ __forceinline__ void async16(void* lds, const void* g) {
    __builtin_amdgcn_global_load_lds(
        (const __attribute__((address_space(1))) unsigned int*)g,
        (__attribute__((address_space(3))) unsigned int*)lds, 16, 0, 0);
}

__device__ __forceinline__ f32x4 mfma16(bf16x8 a, bf16x8 b, f32x4 c) {
    return __builtin_amdgcn_mfma_f32_16x16x32_bf16(a, b, c, 0, 0, 0);
}

// ---------------------------- fused convert fp32 -> bf16 (w/ scale) --------
struct CvtArgs {
    const float* src[7];
    __bf16* dst[7];
    int n4[7];
    float scale[7];
};
__global__ void cvt_all(CvtArgs a) {
    const int t = blockIdx.y;
    const float* __restrict__ src = a.src[t];
    __bf16* __restrict__ dst = a.dst[t];
    const int n4 = a.n4[t];
    const float sc = a.scale[t];
    const int stride = gridDim.x * blockDim.x;
    for (int i = blockIdx.x * blockDim.x + threadIdx.x; i < n4; i += stride) {
        float4 v = ((const float4*)src)[i];
        bf16x4 o;
        o[0] = (__bf16)(v.x * sc); o[1] = (__bf16)(v.y * sc);
        o[2] = (__bf16)(v.z * sc); o[3] = (__bf16)(v.w * sc);
        ((bf16x4*)dst)[i] = o;
    }
}

// ---------------------------- mask all-nonzero flag ------------------------
__global__ void mask_allones(const int* __restrict__ mask, int n4, unsigned int* __restrict__ flag) {
    int stride = gridDim.x * blockDim.x;
    bool ok = true;
    for (int i = blockIdx.x * blockDim.x + threadIdx.x; i < n4; i += stride) {
        int4 v = ((const int4*)mask)[i];
        ok = ok && v.x && v.y && v.z && v.w;
    }
    if (!ok) atomicAnd(flag, 0u);
}

// ---------------------------- GEMM core: 128x64x64 dbuf --------------------
// 256 threads (4 waves 2x2), per-wave 64x32 output. 48KB LDS -> 3 blocks/CU.
template <typename CT>
__device__ __forceinline__ void gemm_core(const char* Ab, const char* Bb, int K,
                                          CT* Cv, size_t crow0, size_t ccol0,
                                          size_t ldc) {
    __shared__ __bf16 At[2][128 * 64];
    __shared__ __bf16 Bt[2][64 * 64];
    const int tid = threadIdx.x;
    const int lane = tid & 63, wv = tid >> 6;
    const int l15 = lane & 15, l4 = lane >> 4;
    const int wr = wv >> 1, wc = wv & 1;
    const int srow = lane >> 3;
    const int sbyte = (((lane & 7) ^ srow) << 4);

    f32x4 acc[4][2];
#pragma unroll
    for (int m = 0; m < 4; m++)
#pragma unroll
        for (int n = 0; n < 2; n++)
#pragma unroll
            for (int r = 0; r < 4; r++) acc[m][n][r] = 0.0f;

    auto stage = [&](int buf, int k0) {
#pragma unroll
        for (int i = 0; i < 6; i++) {
            int c = wv * 6 + i;
            if (c < 16) {
                int row = c * 8 + srow;
                async16(&At[buf][c * 512], Ab + ((size_t)row * K + k0) * 2 + sbyte);
            } else {
                int row = (c - 16) * 8 + srow;
                async16(&Bt[buf][(c - 16) * 512], Bb + ((size_t)row * K + k0) * 2 + sbyte);
            }
        }
    };

    stage(0, 0);
    __syncthreads();
    int cur = 0;
    for (int k0 = 0; k0 < K; k0 += 64) {
        if (k0 + 64 < K) stage(cur ^ 1, k0 + 64);
#pragma unroll
        for (int kk = 0; kk < 2; kk++) {
            bf16x8 af[4], bfr[2];
#pragma unroll
            for (int m = 0; m < 4; m++) {
                int row = wr * 64 + m * 16 + l15;
                int col = (kk * 32 + l4 * 8) ^ ((row & 7) << 3);
                af[m] = *(const bf16x8*)&At[cur][row * 64 + col];
            }
#pragma unroll
            for (int n = 0; n < 2; n++) {
                int row = wc * 32 + n * 16 + l15;
                int col = (kk * 32 + l4 * 8) ^ ((row & 7) << 3);
                bfr[n] = *(const bf16x8*)&Bt[cur][row * 64 + col];
            }
#pragma unroll
            for (int m = 0; m < 4; m++)
#pragma unroll
                for (int n = 0; n < 2; n++)
                    acc[m][n] = mfma16(af[m], bfr[n], acc[m][n]);
        }
        __syncthreads();
        cur ^= 1;
    }

#pragma unroll
    for (int m = 0; m < 4; m++)
#pragma unroll
        for (int n = 0; n < 2; n++)
#pragma unroll
            for (int r = 0; r < 4; r++) {
                size_t row = crow0 + wr * 64 + m * 16 + l4 * 4 + r;
                size_t col = ccol0 + wc * 32 + n * 16 + l15;
                Cv[row * ldc + col] = (CT)acc[m][n][r];
            }
}

// fused QKV projection: C[4096][3072] = A_sel @ W[3072][1024]^T, bn 0..47
__global__ __launch_bounds__(256, 2) void gemm_qkv(const __bf16* __restrict__ Xq,
                                                   const __bf16* __restrict__ Xk,
                                                   const __bf16* __restrict__ Xv,
                                                   const __bf16* __restrict__ W,
                                                   __bf16* __restrict__ C) {
    const int bm = blockIdx.x, bn = blockIdx.y;
    const __bf16* A = (bn < 16) ? Xq : (bn < 32) ? Xk : Xv;
    gemm_core<__bf16>((const char*)(A + (size_t)bm * 128 * DMODEL),
                      (const char*)(W + (size_t)bn * 64 * DMODEL), DMODEL,
                      C, (size_t)bm * 128, (size_t)bn * 64, D3);
}

// out GEMM: out[4096][1024] = ATT @ Wo^T, fp32 out, bn 0..15
__global__ __launch_bounds__(256, 2) void gemm_out(const __bf16* __restrict__ A,
                                                   const __bf16* __restrict__ B,
                                                   float* __restrict__ Cv) {
    const int bm = blockIdx.x, bn = blockIdx.y;
    gemm_core<float>((const char*)(A + (size_t)bm * 128 * DMODEL),
                     (const char*)(B + (size_t)bn * 64 * DMODEL), DMODEL,
                     Cv, (size_t)bm * 128, (size_t)bn * 64, DMODEL);
}

// ---------------------------- V transpose ----------------------------------
// QKV[(s*BS+b)*3072 + 2048 + h*64 + d]  ->  Vt[((b*16+h)*64 + d)*2048 + s]
__global__ __launch_bounds__(256) void transpose_v(const __bf16* __restrict__ QKV,
                                                   __bf16* __restrict__ Vt) {
    __shared__ __bf16 t[64][72];
    const int stile = blockIdx.x;
    const int bh = blockIdx.y;
    const int b = bh >> 4, h = bh & 15;
    const int tid = threadIdx.x;
    {
        int sr = tid >> 2, d0 = (tid & 3) * 16;
        const __bf16* src = QKV + ((size_t)((stile * 64 + sr) * BSZ + b) * D3 + 2 * DMODEL + h * 64 + d0);
        *(bf16x8*)&t[sr][d0]     = *(const bf16x8*)src;
        *(bf16x8*)&t[sr][d0 + 8] = *(const bf16x8*)(src + 8);
    }
    __syncthreads();
    {
        int d = tid >> 2, s0 = (tid & 3) * 16;
        bf16x8 o1, o2;
#pragma unroll
        for (int j = 0; j < 8; j++) { o1[j] = t[s0 + j][d]; o2[j] = t[s0 + 8 + j][d]; }
        __bf16* dst = Vt + ((size_t)(bh * 64 + d) * SLEN + stile * 64 + s0);
        *(bf16x8*)dst = o1;
        *(bf16x8*)(dst + 8) = o2;
    }
}

// ---------------------------- attention ------------------------------------
// grid 512; XCD swizzle: blk&7 -> xcd, all 16 qtiles of a bh on one XCD.
// QBLK=128 (4 waves x 32 q), KBLK=128 staged (2x64-k halves), dbuf, 16 barriers.
__global__ __launch_bounds__(256, 2) void attn_fwd(const __bf16* __restrict__ QKV,
                                                   const __bf16* __restrict__ Vt,
                                                   const int* __restrict__ mask,
                                                   const unsigned int* __restrict__ flag,
                                                   __bf16* __restrict__ Attn) {
    __shared__ __bf16 Kt[2][2][64 * 64];   // [buf][kh][k][d]
    __shared__ __bf16 Vs[2][2][64 * 64];   // [buf][kh][d][k]
    __shared__ __bf16 Ps[128 * 64];        // [q][k64] (wave-private rows)
    const int tid = threadIdx.x;
    const int lane = tid & 63, wv = tid >> 6;
    const int l15 = lane & 15, l4 = lane >> 4;
    // XCD swizzle: 512 blocks, 8 XCDs, 64 blocks/XCD = 4 bh x 16 qt
    const int blk = blockIdx.x;
    const int xcd = blk & 7, idx = blk >> 3;
    const int bh = xcd + (idx >> 4) * 8;
    const int qt = idx & 15;
    const int b = bh >> 4, h = bh & 15;
    const bool allones = (*flag != 0u);
    const int srow = lane >> 3;
    const int sbyte = (((lane & 7) ^ srow) << 4);

    // Q fragments in registers (per wave: 32 rows x 64 d)
    bf16x8 aq[2][2];
#pragma unroll
    for (int m = 0; m < 2; m++)
#pragma unroll
        for (int kk = 0; kk < 2; kk++) {
            int qrow = qt * 128 + wv * 32 + m * 16 + l15;
            aq[m][kk] = *(const bf16x8*)(QKV + ((size_t)(qrow * BSZ + b) * D3 + h * 64 + kk * 32 + l4 * 8));
        }

    f32x4 o[2][4], lr[2];
#pragma unroll
    for (int m = 0; m < 2; m++) {
#pragma unroll
        for (int nd = 0; nd < 4; nd++)
#pragma unroll
            for (int r = 0; r < 4; r++) o[m][nd][r] = 0.0f;
#pragma unroll
        for (int r = 0; r < 4; r++) lr[m][r] = 0.0f;
    }

    const char* Kb = (const char*)QKV + ((size_t)b * D3 + DMODEL + h * 64) * 2;
    const char* Vb = (const char*)Vt + ((size_t)bh * 64) * SLEN * 2;

    // stage one 128-k tile: 16 K chunks + 16 V chunks over 4 waves
    auto stage = [&](int buf, int kt) {
#pragma unroll
        for (int i = 0; i < 8; i++) {
            int c = wv * 8 + i;  // 0..31
            if (c < 16) {
                int kh = c >> 3, ck = c & 7;
                int krow = kt * 128 + kh * 64 + ck * 8 + srow;
                async16(&Kt[buf][kh][ck * 512],
                        Kb + (size_t)krow * (BSZ * D3 * 2) + sbyte);
            } else {
                int c2 = c - 16;
                int kh = c2 >> 3, ck = c2 & 7;
                int drow = ck * 8 + srow;
                async16(&Vs[buf][kh][ck * 512],
                        Vb + (size_t)drow * (SLEN * 2) + kt * 256 + kh * 128 + sbyte);
            }
        }
    };

    stage(0, 0);
    __syncthreads();
    int cur = 0;

    for (int kt = 0; kt < SLEN / 128; kt++) {
        if (kt + 1 < SLEN / 128) stage(cur ^ 1, kt + 1);

#pragma unroll
        for (int kh = 0; kh < 2; kh++) {
            const __bf16* Kl = Kt[cur][kh];
            const __bf16* Vl = Vs[cur][kh];

            // S = Q K^T  (per wave: 32 q x 64 k)
            f32x4 s[2][4];
#pragma unroll
            for (int m = 0; m < 2; m++)
#pragma unroll
                for (int n = 0; n < 4; n++)
#pragma unroll
                    for (int r = 0; r < 4; r++) s[m][n][r] = 0.0f;
            __builtin_amdgcn_s_setprio(1);
#pragma unroll
            for (int n = 0; n < 4; n++) {
                int row = n * 16 + l15;
#pragma unroll
                for (int kk = 0; kk < 2; kk++) {
                    int col = (kk * 32 + l4 * 8) ^ ((row & 7) << 3);
                    bf16x8 bk = *(const bf16x8*)&Kl[row * 64 + col];
#pragma unroll
                    for (int m = 0; m < 2; m++)
                        s[m][n] = mfma16(aq[m][kk], bk, s[m][n]);
                }
            }
            __builtin_amdgcn_s_setprio(0);

            if (!allones) {
#pragma unroll
                for (int m = 0; m < 2; m++)
#pragma unroll
                    for (int n = 0; n < 4; n++)
#pragma unroll
                        for (int r = 0; r < 4; r++) {
                            int q = qt * 128 + wv * 32 + m * 16 + l4 * 4 + r;
                            int kg = kt * 128 + kh * 64 + n * 16 + l15;
                            if (mask[(size_t)q * SLEN + kg] == 0) s[m][n][r] = -1e20f;
                        }
            }

            // exp2-direct softmax (log2e folded into Wq)
#pragma unroll
            for (int m = 0; m < 2; m++)
#pragma unroll
                for (int n = 0; n < 4; n++)
#pragma unroll
                    for (int r = 0; r < 4; r++) {
                        float p = __builtin_amdgcn_exp2f(s[m][n][r]);
                        s[m][n][r] = p;
                        lr[m][r] += p;
                        int row = wv * 32 + m * 16 + l4 * 4 + r;
                        int col = (n * 16 + l15) ^ ((row & 7) << 3);
                        Ps[row * 64 + col] = (__bf16)p;
                    }

            // O += P V
            __builtin_amdgcn_s_setprio(1);
#pragma unroll
            for (int ks = 0; ks < 2; ks++) {
                bf16x8 ap[2];
#pragma unroll
                for (int m = 0; m < 2; m++) {
                    int prow = wv * 32 + m * 16 + l15;
                    int pcol = (ks * 32 + l4 * 8) ^ ((prow & 7) << 3);
                    ap[m] = *(const bf16x8*)&Ps[prow * 64 + pcol];
                }
#pragma unroll
                for (int nd = 0; nd < 4; nd++) {
                    int vrow = nd * 16 + l15;
                    int vcol = (ks * 32 + l4 * 8) ^ ((vrow & 7) << 3);
                    bf16x8 bv = *(const bf16x8*)&Vl[vrow * 64 + vcol];
#pragma unroll
                    for (int m = 0; m < 2; m++)
                        o[m][nd] = mfma16(ap[m], bv, o[m][nd]);
                }
            }
            __builtin_amdgcn_s_setprio(0);
        }

        __syncthreads();
        cur ^= 1;
    }

    // final row-sum reduce across the 16-lane k-slices, normalize + store
#pragma unroll
    for (int d = 1; d < 16; d <<= 1)
#pragma unroll
        for (int m = 0; m < 2; m++)
#pragma unroll
            for (int r = 0; r < 4; r++) lr[m][r] += __shfl_xor(lr[m][r], d);

#pragma unroll
    for (int m = 0; m < 2; m++) {
        f32x4 inv;
#pragma unroll
        for (int r = 0; r < 4; r++) inv[r] = 1.0f / lr[m][r];
#pragma unroll
        for (int nd = 0; nd < 4; nd++)
#pragma unroll
            for (int r = 0; r < 4; r++) {
                int qrow = qt * 128 + wv * 32 + m * 16 + l4 * 4 + r;
                Attn[((size_t)(qrow * BSZ + b)) * DMODEL + h * 64 + nd * 16 + l15] =
                    (__bf16)(o[m][nd][r] * inv[r]);
            }
    }
}

// ---------------------------- launcher -------------------------------------
extern "C" void kernel_launch(void* const* d_in, const int* in_sizes, int n_in,
                              void* d_out, int out_size, void* d_ws, size_t ws_size,
                              hipStream_t stream) {
    const float* query  = (const float*)d_in[0];
    const float* keys   = (const float*)d_in[1];
    const float* values = (const float*)d_in[2];
    const int*   mask   = (const int*)d_in[3];
    const float* Wq     = (const float*)d_in[4];
    const float* Wk     = (const float*)d_in[5];
    const float* Wv     = (const float*)d_in[6];
    const float* Wo     = (const float*)d_in[7];
    float* out = (float*)d_out;

    char* ws = (char*)d_ws;
    const size_t MB = 1024 * 1024;
    __bf16* XQ   = (__bf16*)(ws + 0);
    __bf16* XK   = (__bf16*)(ws + 8 * MB);
    __bf16* XV   = (__bf16*)(ws + 16 * MB);
    __bf16* WCAT = (__bf16*)(ws + 24 * MB);   // [3072][1024]: Wq|Wk|Wv
    __bf16* WQB  = WCAT;
    __bf16* WKB  = (__bf16*)(ws + 26 * MB);
    __bf16* WVB  = (__bf16*)(ws + 28 * MB);
    __bf16* WOB  = (__bf16*)(ws + 30 * MB);
    __bf16* QKV  = (__bf16*)(ws + 32 * MB);   // [4096][3072] = 24 MB
    __bf16* VT   = (__bf16*)(ws + 0);         // reuse XQ (free after gemm_qkv)
    __bf16* ATT  = (__bf16*)(ws + 8 * MB);    // reuse XK
    unsigned int* flag = (unsigned int*)(ws + 56 * MB);

    (void)hipMemsetAsync(flag, 0xFF, 4, stream);

    const int NTOK = SLEN * BSZ;  // 4096
    const int NBIG = NTOK * DMODEL / 4, NW = DMODEL * DMODEL / 4;
    const float LOG2E = 1.4426950408889634f;
    CvtArgs ca;
    ca.src[0] = query;  ca.dst[0] = XQ;  ca.n4[0] = NBIG; ca.scale[0] = 1.0f;
    ca.src[1] = keys;   ca.dst[1] = XK;  ca.n4[1] = NBIG; ca.scale[1] = 1.0f;
    ca.src[2] = values; ca.dst[2] = XV;  ca.n4[2] = NBIG; ca.scale[2] = 1.0f;
    ca.src[3] = Wq;     ca.dst[3] = WQB; ca.n4[3] = NW;   ca.scale[3] = LOG2E;
    ca.src[4] = Wk;     ca.dst[4] = WKB; ca.n4[4] = NW;   ca.scale[4] = 1.0f;
    ca.src[5] = Wv;     ca.dst[5] = WVB; ca.n4[5] = NW;   ca.scale[5] = 1.0f;
    ca.src[6] = Wo;     ca.dst[6] = WOB; ca.n4[6] = NW;   ca.scale[6] = 1.0f;
    cvt_all<<<dim3(256, 7), 256, 0, stream>>>(ca);

    mask_allones<<<512, 256, 0, stream>>>(mask, SLEN * SLEN / 4, flag);

    // fused QKV projection: grid (32, 48) = 1536 blocks (128x64 tiles)
    gemm_qkv<<<dim3(NTOK / 128, D3 / 64), 256, 0, stream>>>(XQ, XK, XV, WCAT, QKV);

    transpose_v<<<dim3(SLEN / 64, BSZ * NHEAD), 256, 0, stream>>>(QKV, VT);

    attn_fwd<<<BSZ * NHEAD * (SLEN / 128), 256, 0, stream>>>(QKV, VT, mask, flag, ATT);

    gemm_out<<<dim3(NTOK / 128, DMODEL / 64), 256, 0, stream>>>(ATT, WOB, out);
}